// Round 1
// baseline (6042.793 us; speedup 1.0000x reference)
//
#include <hip/hip_runtime.h>

// LSTM_584115552367: B=65536, T=50, D=17, SLB=30 (read at runtime).
// One thread per batch element; weights staged (and algebraically combined)
// in LDS; fp32 VALU throughout. Compute floor ~108 us at 157 TF fp32.

#define Dn 17
#define Gn 68          // 4*D
#define Tn 50
#define RS 20          // padded LDS row stride (80 B, 16B-aligned rows)

__device__ __forceinline__ float sigm_(float v) {
    float e = __expf(-v);
    return __builtin_amdgcn_rcpf(1.0f + e);
}
__device__ __forceinline__ float tanh_(float v) {
    // 1 - 2/(exp(2v)+1); saturates correctly at +/-inf
    float e = __expf(2.0f * v);
    return 1.0f - 2.0f * __builtin_amdgcn_rcpf(e + 1.0f);
}

__global__ __launch_bounds__(256, 1)
void lstm_fused(const float* __restrict__ x,
                const float* __restrict__ W_ih,
                const float* __restrict__ W_hh,
                const float* __restrict__ b_ih,
                const float* __restrict__ b_hh,
                const float* __restrict__ W_lin,
                const float* __restrict__ b_lin,
                const float* __restrict__ m_ih,
                const float* __restrict__ m_hh,
                const int*   __restrict__ slb_p,
                float* __restrict__ out)
{
    // sA = W_ih*mask, sB = W_hh*mask, sC = sB + sA @ W_lin (free-running fold)
    __shared__ __align__(16) float sA[Gn * RS];
    __shared__ __align__(16) float sB[Gn * RS];
    __shared__ __align__(16) float sC[Gn * RS];
    __shared__ __align__(16) float sWl[Dn * RS];
    __shared__ float sbs[Gn];   // b_ih + b_hh
    __shared__ float sbc[Gn];   // sbs + sA @ b_lin
    __shared__ float sbl[Dn];

    const int tid = threadIdx.x;

    for (int i = tid; i < Gn * Dn; i += 256) {
        int j = i / Dn, k = i - j * Dn;
        sA[j * RS + k] = W_ih[i] * m_ih[i];
        sB[j * RS + k] = W_hh[i] * m_hh[i];
    }
    for (int i = tid; i < Dn * Dn; i += 256) {
        int j = i / Dn, k = i - j * Dn;
        sWl[j * RS + k] = W_lin[i];
    }
    if (tid < Gn) sbs[tid] = b_ih[tid] + b_hh[tid];
    if (tid < Dn) sbl[tid] = b_lin[tid];
    __syncthreads();

    // C[j,m] = B[j,m] + sum_k A[j,k] * W_lin[k,m]
    for (int i = tid; i < Gn * Dn; i += 256) {
        int j = i / Dn, m = i - j * Dn;
        float s = sB[j * RS + m];
        #pragma unroll
        for (int k = 0; k < Dn; ++k)
            s += sA[j * RS + k] * sWl[k * RS + m];
        sC[j * RS + m] = s;
    }
    // bc[j] = bs[j] + sum_k A[j,k] * b_lin[k]
    for (int j = tid; j < Gn; j += 256) {
        float s = sbs[j];
        #pragma unroll
        for (int k = 0; k < Dn; ++k) s += sA[j * RS + k] * sbl[k];
        sbc[j] = s;
    }
    __syncthreads();

    const int b = blockIdx.x * 256 + tid;
    const float* __restrict__ xr = x + (size_t)b * (Tn * Dn);
    const int slb = slb_p[0];

    float h[Dn], c[Dn];
    #pragma unroll
    for (int k = 0; k < Dn; ++k) { h[k] = 0.0f; c[k] = 0.0f; }

    // Phase 1: teacher-forced, t in [0, slb). No linear head needed.
    float xi[Dn];
    #pragma unroll
    for (int k = 0; k < Dn; ++k) xi[k] = xr[k];

    for (int t = 0; t < slb; ++t) {
        float xn[Dn];
        if (t + 1 < slb) {
            #pragma unroll
            for (int k = 0; k < Dn; ++k) xn[k] = xr[(t + 1) * Dn + k];
        } else {
            #pragma unroll
            for (int k = 0; k < Dn; ++k) xn[k] = 0.0f;
        }
        float hn[Dn];
        #pragma unroll
        for (int e = 0; e < Dn; ++e) {
            float gi = sbs[e];
            float gf = sbs[Dn + e];
            float gg = sbs[2 * Dn + e];
            float go = sbs[3 * Dn + e];
            #pragma unroll
            for (int k = 0; k < Dn; ++k) {
                float xv = xi[k], hv = h[k];
                gi += xv * sA[e * RS + k];
                gf += xv * sA[(Dn + e) * RS + k];
                gg += xv * sA[(2 * Dn + e) * RS + k];
                go += xv * sA[(3 * Dn + e) * RS + k];
                gi += hv * sB[e * RS + k];
                gf += hv * sB[(Dn + e) * RS + k];
                gg += hv * sB[(2 * Dn + e) * RS + k];
                go += hv * sB[(3 * Dn + e) * RS + k];
            }
            float cv = sigm_(gf) * c[e] + sigm_(gi) * tanh_(gg);
            c[e] = cv;
            hn[e] = sigm_(go) * tanh_(cv);
        }
        #pragma unroll
        for (int k = 0; k < Dn; ++k) { h[k] = hn[k]; xi[k] = xn[k]; }
    }

    // Phase 2: free-running, t in [slb, T). gates = C @ h + bc; emit linear head.
    const int nout = Tn - slb;
    float* __restrict__ op = out + (size_t)b * (size_t)nout * Dn;
    for (int t = 0; t < nout; ++t) {
        float hn[Dn];
        #pragma unroll
        for (int e = 0; e < Dn; ++e) {
            float gi = sbc[e];
            float gf = sbc[Dn + e];
            float gg = sbc[2 * Dn + e];
            float go = sbc[3 * Dn + e];
            #pragma unroll
            for (int k = 0; k < Dn; ++k) {
                float hv = h[k];
                gi += hv * sC[e * RS + k];
                gf += hv * sC[(Dn + e) * RS + k];
                gg += hv * sC[(2 * Dn + e) * RS + k];
                go += hv * sC[(3 * Dn + e) * RS + k];
            }
            float cv = sigm_(gf) * c[e] + sigm_(gi) * tanh_(gg);
            c[e] = cv;
            hn[e] = sigm_(go) * tanh_(cv);
        }
        #pragma unroll
        for (int k = 0; k < Dn; ++k) h[k] = hn[k];
        #pragma unroll
        for (int cc = 0; cc < Dn; ++cc) {
            float s = sbl[cc];
            #pragma unroll
            for (int k = 0; k < Dn; ++k) s += h[k] * sWl[cc * RS + k];
            op[t * Dn + cc] = s;
        }
    }
}

extern "C" void kernel_launch(void* const* d_in, const int* in_sizes, int n_in,
                              void* d_out, int out_size, void* d_ws, size_t ws_size,
                              hipStream_t stream) {
    (void)in_sizes; (void)n_in; (void)d_ws; (void)ws_size; (void)out_size;
    const float* x     = (const float*)d_in[0];
    const float* W_ih  = (const float*)d_in[1];
    const float* W_hh  = (const float*)d_in[2];
    const float* b_ih  = (const float*)d_in[3];
    const float* b_hh  = (const float*)d_in[4];
    const float* W_lin = (const float*)d_in[5];
    const float* b_lin = (const float*)d_in[6];
    const float* m_ih  = (const float*)d_in[7];
    const float* m_hh  = (const float*)d_in[8];
    const int*   slb   = (const int*)d_in[9];
    float* out = (float*)d_out;

    lstm_fused<<<dim3(256), dim3(256), 0, stream>>>(
        x, W_ih, W_hh, b_ih, b_hh, W_lin, b_lin, m_ih, m_hh, slb, out);
}

// Round 2
// 762.717 us; speedup vs baseline: 7.9227x; 7.9227x over previous
//
#include <hip/hip_runtime.h>

// LSTM_584115552367 — B=65536, T=50, D=17, SLB=30 (runtime).
// 1 thread / batch element. Outer-product gates with wave-uniform float4
// weight broadcasts from LDS; x and out coalesced via LDS transpose staging.

#define Dn 17
#define Gn 68
#define Tn 50
#define WS 68          // gate-row width (17 float4, 272 B rows, 16B-aligned)
#define ZS 51          // zbuf row stride: [x_even 17 | x_odd 17 | h 17]; odd -> conflict-free
#define HOFF 34

__device__ __forceinline__ float sigm_(float v) {
    float e = __expf(-v);
    return __builtin_amdgcn_rcpf(1.0f + e);
}
__device__ __forceinline__ float tanh_(float v) {
    float e = __expf(2.0f * v);
    return 1.0f - 2.0f * __builtin_amdgcn_rcpf(e + 1.0f);
}
__device__ __forceinline__ float getc(const float4 v, int c) {
    return c == 0 ? v.x : c == 1 ? v.y : c == 2 ? v.z : v.w;
}
__device__ __forceinline__ void fma4(float4& a, float b, const float4 w) {
    a.x = __builtin_fmaf(b, w.x, a.x);
    a.y = __builtin_fmaf(b, w.y, a.y);
    a.z = __builtin_fmaf(b, w.z, a.z);
    a.w = __builtin_fmaf(b, w.w, a.w);
}

__global__ __launch_bounds__(256, 1)
void lstm_fused(const float* __restrict__ x,
                const float* __restrict__ W_ih, const float* __restrict__ W_hh,
                const float* __restrict__ b_ih, const float* __restrict__ b_hh,
                const float* __restrict__ W_lin, const float* __restrict__ b_lin,
                const float* __restrict__ m_ih, const float* __restrict__ m_hh,
                const int* __restrict__ slb_p, float* __restrict__ out)
{
    __shared__ __align__(16) float sWzT[2 * Dn * WS];  // rows k<17: A^T(x part); 17..33: B^T(h part)
    __shared__ __align__(16) float sCzT[Dn * WS];      // free-running fold: C = B + A@Wlin, transposed
    __shared__ __align__(16) float sWlT[Dn * 20];      // Wlin^T rows padded to 20
    __shared__ __align__(16) float sBs[WS];            // b_ih + b_hh
    __shared__ __align__(16) float sBc[WS];            // folded phase-2 bias
    __shared__ __align__(16) float sBl[20];            // b_lin (padded)
    __shared__ float tmpA[Gn * Dn];
    __shared__ float tmpB[Gn * Dn];
    __shared__ float zbuf[256 * ZS];
    __shared__ float obuf[256 * Dn];

    const int tid = threadIdx.x;
    const int b0  = blockIdx.x * 256;

    // ---- setup: masked weights, transposes, free-running fold ----
    for (int i = tid; i < Gn * Dn; i += 256) {
        tmpA[i] = W_ih[i] * m_ih[i];
        tmpB[i] = W_hh[i] * m_hh[i];
    }
    for (int i = tid; i < Dn * 20; i += 256) {
        int k = i / 20, m = i - 20 * k;
        sWlT[i] = (m < Dn) ? W_lin[m * Dn + k] : 0.0f;
    }
    if (tid < WS) sBs[tid] = b_ih[tid] + b_hh[tid];
    if (tid < 20) sBl[tid] = (tid < Dn) ? b_lin[tid] : 0.0f;
    __syncthreads();
    for (int i = tid; i < 2 * Dn * WS; i += 256) {
        int k = i / WS, j = i - WS * k;
        sWzT[i] = (k < Dn) ? tmpA[j * Dn + k] : tmpB[j * Dn + (k - Dn)];
    }
    for (int i = tid; i < Dn * WS; i += 256) {
        int k = i / WS, j = i - WS * k;
        float v = tmpB[j * Dn + k];
        #pragma unroll
        for (int m = 0; m < Dn; ++m) v = __builtin_fmaf(tmpA[j * Dn + m], sWlT[k * 20 + m], v);
        sCzT[i] = v;
    }
    if (tid < Gn) {
        float v = sBs[tid];
        #pragma unroll
        for (int m = 0; m < Dn; ++m) v = __builtin_fmaf(tmpA[tid * Dn + m], sBl[m], v);
        sBc[tid] = v;
    }

    // ---- init state; stage x(t=0) transposed into parity-0 slots ----
    #pragma unroll
    for (int e = 0; e < Dn; ++e) zbuf[tid * ZS + HOFF + e] = 0.0f;
    int offx[17], brow_[17], dcol_[17];
    #pragma unroll
    for (int i = 0; i < 17; ++i) {
        int f = tid + 256 * i;           // 0..4351 covers 256 rows x 17
        int br = f / 17, d = f - 17 * br;
        brow_[i] = br; dcol_[i] = d;
        offx[i] = ((b0 + br) * Tn) * Dn + d;
        zbuf[br * ZS + d] = x[offx[i]];  // t=0, parity 0
    }
    __syncthreads();

    const int slb = slb_p[0];
    float c[Dn];
    #pragma unroll
    for (int e = 0; e < Dn; ++e) c[e] = 0.0f;
    const float* zr = &zbuf[tid * ZS];
    const float4* bs4 = (const float4*)sBs;

    // ---- phase 1: teacher-forced ----
    for (int t = 0; t < slb; ++t) {
        float gx[17];
        const bool pre = (t + 1 < Tn);
        if (pre) {
            #pragma unroll
            for (int i = 0; i < 17; ++i) gx[i] = x[offx[i] + (t + 1) * Dn];
        }
        float4 acc[17];
        #pragma unroll
        for (int j = 0; j < 17; ++j) acc[j] = bs4[j];
        const int xo = (t & 1) * Dn;
        #pragma unroll 2
        for (int k = 0; k < Dn; ++k) {           // x part
            float zk = zr[xo + k];
            const float4* w4 = (const float4*)&sWzT[k * WS];
            #pragma unroll
            for (int j = 0; j < 17; ++j) fma4(acc[j], zk, w4[j]);
        }
        #pragma unroll 2
        for (int k = 0; k < Dn; ++k) {           // h part
            float zk = zr[HOFF + k];
            const float4* w4 = (const float4*)&sWzT[(Dn + k) * WS];
            #pragma unroll
            for (int j = 0; j < 17; ++j) fma4(acc[j], zk, w4[j]);
        }
        #pragma unroll
        for (int e = 0; e < Dn; ++e) {
            float gi = getc(acc[e >> 2], e & 3);
            float gf = getc(acc[(Dn + e) >> 2], (Dn + e) & 3);
            float gg = getc(acc[(2 * Dn + e) >> 2], (2 * Dn + e) & 3);
            float go = getc(acc[(3 * Dn + e) >> 2], (3 * Dn + e) & 3);
            float cv = __builtin_fmaf(sigm_(gf), c[e], sigm_(gi) * tanh_(gg));
            c[e] = cv;
            zbuf[tid * ZS + HOFF + e] = sigm_(go) * tanh_(cv);
        }
        if (pre) {
            const int xo2 = ((t + 1) & 1) * Dn;
            #pragma unroll
            for (int i = 0; i < 17; ++i) zbuf[brow_[i] * ZS + xo2 + dcol_[i]] = gx[i];
        }
        __syncthreads();
    }

    // ---- phase 2: free-running ----
    const int nout = Tn - slb;
    int offo[17];
    #pragma unroll
    for (int i = 0; i < 17; ++i) offo[i] = ((b0 + brow_[i]) * nout) * Dn + dcol_[i];
    const float4* bc4 = (const float4*)sBc;
    const float4* bl4 = (const float4*)sBl;

    for (int tp = 0; tp < nout; ++tp) {
        float4 acc[17];
        #pragma unroll
        for (int j = 0; j < 17; ++j) acc[j] = bc4[j];
        #pragma unroll 2
        for (int k = 0; k < Dn; ++k) {
            float zk = zr[HOFF + k];
            const float4* w4 = (const float4*)&sCzT[k * WS];
            #pragma unroll
            for (int j = 0; j < 17; ++j) fma4(acc[j], zk, w4[j]);
        }
        float hn[Dn];
        #pragma unroll
        for (int e = 0; e < Dn; ++e) {
            float gi = getc(acc[e >> 2], e & 3);
            float gf = getc(acc[(Dn + e) >> 2], (Dn + e) & 3);
            float gg = getc(acc[(2 * Dn + e) >> 2], (2 * Dn + e) & 3);
            float go = getc(acc[(3 * Dn + e) >> 2], (3 * Dn + e) & 3);
            float cv = __builtin_fmaf(sigm_(gf), c[e], sigm_(gi) * tanh_(gg));
            c[e] = cv;
            hn[e] = sigm_(go) * tanh_(cv);
            zbuf[tid * ZS + HOFF + e] = hn[e];
        }
        // linear head from registers (fully unrolled so hn stays in regs)
        float4 o4[5];
        #pragma unroll
        for (int j = 0; j < 5; ++j) o4[j] = bl4[j];
        #pragma unroll
        for (int k = 0; k < Dn; ++k) {
            const float4* w4 = (const float4*)&sWlT[k * 20];
            #pragma unroll
            for (int j = 0; j < 5; ++j) fma4(o4[j], hn[k], w4[j]);
        }
        #pragma unroll
        for (int m = 0; m < Dn; ++m) obuf[tid * Dn + m] = getc(o4[m >> 2], m & 3);
        __syncthreads();
        #pragma unroll
        for (int i = 0; i < 17; ++i) out[offo[i] + tp * Dn] = obuf[tid + 256 * i];
        __syncthreads();
    }
}

extern "C" void kernel_launch(void* const* d_in, const int* in_sizes, int n_in,
                              void* d_out, int out_size, void* d_ws, size_t ws_size,
                              hipStream_t stream) {
    (void)in_sizes; (void)n_in; (void)d_ws; (void)ws_size; (void)out_size;
    const float* x     = (const float*)d_in[0];
    const float* W_ih  = (const float*)d_in[1];
    const float* W_hh  = (const float*)d_in[2];
    const float* b_ih  = (const float*)d_in[3];
    const float* b_hh  = (const float*)d_in[4];
    const float* W_lin = (const float*)d_in[5];
    const float* b_lin = (const float*)d_in[6];
    const float* m_ih  = (const float*)d_in[7];
    const float* m_hh  = (const float*)d_in[8];
    const int*   slb   = (const int*)d_in[9];
    float* out = (float*)d_out;

    lstm_fused<<<dim3(256), dim3(256), 0, stream>>>(
        x, W_ih, W_hh, b_ih, b_hh, W_lin, b_lin, m_ih, m_hh, slb, out);
}